// Round 3
// baseline (102.351 us; speedup 1.0000x reference)
//
#include <hip/hip_runtime.h>

#define B_ 4
#define R_ 48
#define VR_ 96
#define ROWF 288                     // floats per gathered row: SoA x[96] y[96] z[96]
#define NROWS (B_ * 2 * R_)          // 384 rows
#define NCELL (B_ * R_ * R_)         // 9216 cells
#define NBLK_CELL (B_ * R_ * 12)     // 2304 blocks, 4 waves (cells) each

typedef float v2f __attribute__((ext_vector_type(2)));

// ws layout: [0, 36KB) minbuf | [40960, +8) ctrl{counter, stride4} | [64KB, +442KB) gbuf

// ---------------------------------------------------------------------------
// Kernel A: compact gather (SoA rows) + control init (counter=0, cmaps layout
// detect). One thread per (b,set,r,v) point.
__global__ __launch_bounds__(256) void gather_kernel(
    const float* __restrict__ v1s, const float* __restrict__ v2s,
    const int* __restrict__ rid_to_vid, const unsigned char* __restrict__ cm,
    float* __restrict__ gbuf, int* __restrict__ ctrl, int N) {
  const int t = threadIdx.x;
  if (blockIdx.x == 0 && t < 64) {
    // Detect cmaps element width from first 256 bytes (wave-parallel).
    // int32 layout: bytes at i%4!=0 all zero; f32 layout: contains 0x80/0x3F;
    // bool layout: random 0/1 bytes, some nonzero, none > 1.
    const unsigned int d = ((const unsigned int*)cm)[t];
    const unsigned int b1 = (d >> 8) & 0xff, b2 = (d >> 16) & 0xff, b3 = d >> 24;
    const unsigned long long nzm = __ballot((b1 | b2 | b3) != 0);
    const unsigned long long bigm = __ballot((b1 > 1) || (b2 > 1) || (b3 > 1));
    if (t == 0) {
      ctrl[0] = 0;                                       // last-block counter
      ctrl[1] = (bigm != 0ull || nzm == 0ull) ? 1 : 0;   // 1 => 4-byte elements
    }
  }
  const int i = blockIdx.x * 256 + t;
  if (i >= NROWS * VR_) return;
  const int v = i % VR_;
  const int row = i / VR_;            // (b*2+set)*48 + r
  const int r = row % R_;
  const int bs = row / R_;
  const int set = bs & 1;
  const int b = bs >> 1;
  const int idx = rid_to_vid[r * VR_ + v];
  const float* src = (set ? v2s : v1s) + ((size_t)b * N + idx) * 3;
  float* dst = gbuf + (size_t)row * ROWF;
  dst[v] = src[0];
  dst[VR_ + v] = src[1];
  dst[2 * VR_ + v] = src[2];
}

// ---------------------------------------------------------------------------
// Kernel B: one wave per (b,r,s) cell, 4 cells/block. Masked-out cells are
// skipped entirely (their min_d is multiplied by 0 in the reference). No LDS
// staging: gbuf is L2-resident, fragments loaded as float4 direct from global.
// Packed-f32 inner loop (v_pk_add/fma) + v_min3 reduction. Last block to
// finish runs the masked-mean finalize (device-scope atomics + fences).
__global__ __launch_bounds__(256) void cell_kernel(
    const float* __restrict__ gbuf, const unsigned char* __restrict__ cm,
    float* __restrict__ minbuf, int* __restrict__ ctrl,
    float* __restrict__ out) {
  const int bid = blockIdx.x;              // b*(48*12) + r*12 + quad
  const int b = bid / (R_ * 12);
  const int rem = bid % (R_ * 12);
  const int r = rem / 12;
  const int quad = rem % 12;
  const int t = threadIdx.x;
  const int w = t >> 6, lane = t & 63;
  const int s = quad * 4 + w;
  const int cellIdx = (b * R_ + r) * R_ + s;

  const int stride4 = ctrl[1];
  const unsigned int* cm32 = (const unsigned int*)cm;
  const bool active = stride4 ? (cm32[cellIdx] != 0u) : (cm[cellIdx] != 0);

  if (active) {                            // wave-uniform branch
    const float* row1 = gbuf + (size_t)((b * 2 + 0) * R_ + r) * ROWF;
    const float* row2 = gbuf + (size_t)((b * 2 + 1) * R_ + s) * ROWF;
    const int hi = lane >> 3, lo = lane & 7;   // 8x8 lane grid, 12x12 pair tile

    float Ax[12], Ay[12], Az[12];
    v2f Bx[6], By[6], Bz[6];
#pragma unroll
    for (int k = 0; k < 3; ++k) {
      *(float4*)&Ax[4 * k] = ((const float4*)(row1       + hi * 12))[k];
      *(float4*)&Ay[4 * k] = ((const float4*)(row1 +  96 + hi * 12))[k];
      *(float4*)&Az[4 * k] = ((const float4*)(row1 + 192 + hi * 12))[k];
      *(float4*)&Bx[2 * k] = ((const float4*)(row2       + lo * 12))[k];
      *(float4*)&By[2 * k] = ((const float4*)(row2 +  96 + lo * 12))[k];
      *(float4*)&Bz[2 * k] = ((const float4*)(row2 + 192 + lo * 12))[k];
    }

    float acc[4] = {3.4e38f, 3.4e38f, 3.4e38f, 3.4e38f};
#pragma unroll
    for (int i = 0; i < 12; ++i) {
      const v2f axx = {Ax[i], Ax[i]};
      const v2f ayy = {Ay[i], Ay[i]};
      const v2f azz = {Az[i], Az[i]};
#pragma unroll
      for (int j = 0; j < 6; ++j) {
        const v2f dx = axx - Bx[j];
        const v2f dy = ayy - By[j];
        const v2f dz = azz - Bz[j];
        const v2f d2 = dx * dx + dy * dy + dz * dz;
        acc[j & 3] = fminf(acc[j & 3], fminf(d2.x, d2.y));   // v_min3
      }
    }
    float mind2 = fminf(fminf(acc[0], acc[1]), fminf(acc[2], acc[3]));
#pragma unroll
    for (int off = 32; off > 0; off >>= 1)
      mind2 = fminf(mind2, __shfl_down(mind2, off, 64));
    if (lane == 0) {
      atomicExch(&minbuf[cellIdx], sqrtf(fmaxf(mind2, 0.0f)));  // device-scope
      __threadfence();
    }
  }

  __syncthreads();
  __shared__ int lastflag;
  if (t == 0) lastflag = (atomicAdd(&ctrl[0], 1) == NBLK_CELL - 1) ? 1 : 0;
  __syncthreads();
  if (!lastflag) return;

  __threadfence();  // acquire: all blocks' minbuf atomics precede our counter hit
  __shared__ float ws_[4], wc_[4];
  for (int bb = 0; bb < B_; ++bb) {
    float sum = 0.0f, cnt = 0.0f;
    for (int i = t; i < R_ * R_; i += 256) {
      const int gi = bb * R_ * R_ + i;
      const bool m = stride4 ? (cm32[gi] != 0u) : (cm[gi] != 0);
      if (m) { sum += minbuf[gi]; cnt += 1.0f; }
    }
#pragma unroll
    for (int off = 32; off > 0; off >>= 1) {
      sum += __shfl_down(sum, off, 64);
      cnt += __shfl_down(cnt, off, 64);
    }
    if ((t & 63) == 0) { ws_[t >> 6] = sum; wc_[t >> 6] = cnt; }
    __syncthreads();
    if (t == 0)
      out[bb] = (ws_[0] + ws_[1] + ws_[2] + ws_[3]) /
                (wc_[0] + wc_[1] + wc_[2] + wc_[3]);
    __syncthreads();   // ws_/wc_ reuse
  }
}

// ---------------------------------------------------------------------------
extern "C" void kernel_launch(void* const* d_in, const int* in_sizes, int n_in,
                              void* d_out, int out_size, void* d_ws, size_t ws_size,
                              hipStream_t stream) {
  const float* v1s = (const float*)d_in[0];
  const float* v2s = (const float*)d_in[1];
  const unsigned char* cmaps = (const unsigned char*)d_in[2];
  const int* rid_to_vid = (const int*)d_in[3];
  float* out = (float*)d_out;

  float* minbuf = (float*)d_ws;
  int* ctrl = (int*)((char*)d_ws + 40960);
  float* gbuf = (float*)((char*)d_ws + (64 << 10));

  const int N = in_sizes[0] / (B_ * 3);

  gather_kernel<<<(NROWS * VR_ + 255) / 256, 256, 0, stream>>>(
      v1s, v2s, rid_to_vid, cmaps, gbuf, ctrl, N);
  cell_kernel<<<NBLK_CELL, 256, 0, stream>>>(gbuf, cmaps, minbuf, ctrl, out);
}

// Round 4
// 25.459 us; speedup vs baseline: 4.0202x; 4.0202x over previous
//
#include <hip/hip_runtime.h>

#define B_ 4
#define R_ 48
#define VR_ 96
#define ROWF 288                     // floats per gathered row: SoA x[96] y[96] z[96]
#define NROWS (B_ * 2 * R_)          // 384 rows
#define NBLK_CELL (B_ * R_ * 12)     // 2304 blocks, 4 waves (cells) each

typedef float v2f __attribute__((ext_vector_type(2)));

// ws layout: [0, 36KB) minbuf | [40960, +8) ctrl{_, stride4} | [64KB, +442KB) gbuf

// ---------------------------------------------------------------------------
// Kernel A: compact gather (SoA rows) + cmaps-layout detect. One thread per
// (b,set,r,v) point.
__global__ __launch_bounds__(256) void gather_kernel(
    const float* __restrict__ v1s, const float* __restrict__ v2s,
    const int* __restrict__ rid_to_vid, const unsigned char* __restrict__ cm,
    float* __restrict__ gbuf, int* __restrict__ ctrl, int N) {
  const int t = threadIdx.x;
  if (blockIdx.x == 0 && t < 64) {
    // Detect cmaps element width from first 256 bytes (wave-parallel).
    // int32 layout: bytes at i%4!=0 all zero; f32 layout: contains 0x80/0x3F;
    // bool layout: random 0/1 bytes, some nonzero, none > 1.
    const unsigned int d = ((const unsigned int*)cm)[t];
    const unsigned int b1 = (d >> 8) & 0xff, b2 = (d >> 16) & 0xff, b3 = d >> 24;
    const unsigned long long nzm = __ballot((b1 | b2 | b3) != 0);
    const unsigned long long bigm = __ballot((b1 > 1) || (b2 > 1) || (b3 > 1));
    if (t == 0) ctrl[1] = (bigm != 0ull || nzm == 0ull) ? 1 : 0;  // 1 => 4-byte
  }
  const int i = blockIdx.x * 256 + t;
  if (i >= NROWS * VR_) return;
  const int v = i % VR_;
  const int row = i / VR_;            // (b*2+set)*48 + r
  const int r = row % R_;
  const int bs = row / R_;
  const int set = bs & 1;
  const int b = bs >> 1;
  const int idx = rid_to_vid[r * VR_ + v];
  const float* src = (set ? v2s : v1s) + ((size_t)b * N + idx) * 3;
  float* dst = gbuf + (size_t)row * ROWF;
  dst[v] = src[0];
  dst[VR_ + v] = src[1];
  dst[2 * VR_ + v] = src[2];
}

// ---------------------------------------------------------------------------
// Kernel B: one wave per (b,r,s) cell, 4 independent waves/block (no LDS, no
// barriers). Masked-out cells exit immediately (their min_d contributes 0).
// Fragments load direct from global (gbuf is L2-resident). Packed-f32 math.
// Plain (non-atomic) store — no fences, no cross-block communication.
__global__ __launch_bounds__(256) void cell_kernel(
    const float* __restrict__ gbuf, const unsigned char* __restrict__ cm,
    float* __restrict__ minbuf, const int* __restrict__ ctrl) {
  const int bid = blockIdx.x;              // b*(48*12) + r*12 + quad
  const int b = bid / (R_ * 12);
  const int rem = bid % (R_ * 12);
  const int r = rem / 12;
  const int quad = rem % 12;
  const int t = threadIdx.x;
  const int w = t >> 6, lane = t & 63;
  const int s = quad * 4 + w;
  const int cellIdx = (b * R_ + r) * R_ + s;

  const bool active = ctrl[1] ? (((const unsigned int*)cm)[cellIdx] != 0u)
                              : (cm[cellIdx] != 0);
  if (!active) return;                     // wave-uniform

  const float* row1 = gbuf + (size_t)((b * 2 + 0) * R_ + r) * ROWF;
  const float* row2 = gbuf + (size_t)((b * 2 + 1) * R_ + s) * ROWF;
  const int hi = lane >> 3, lo = lane & 7;     // 8x8 lane grid, 12x12 pair tile

  float Ax[12], Ay[12], Az[12];
  v2f Bx[6], By[6], Bz[6];
#pragma unroll
  for (int k = 0; k < 3; ++k) {
    *(float4*)&Ax[4 * k] = ((const float4*)(row1       + hi * 12))[k];
    *(float4*)&Ay[4 * k] = ((const float4*)(row1 +  96 + hi * 12))[k];
    *(float4*)&Az[4 * k] = ((const float4*)(row1 + 192 + hi * 12))[k];
    *(float4*)&Bx[2 * k] = ((const float4*)(row2       + lo * 12))[k];
    *(float4*)&By[2 * k] = ((const float4*)(row2 +  96 + lo * 12))[k];
    *(float4*)&Bz[2 * k] = ((const float4*)(row2 + 192 + lo * 12))[k];
  }

  float acc[4] = {3.4e38f, 3.4e38f, 3.4e38f, 3.4e38f};
#pragma unroll
  for (int i = 0; i < 12; ++i) {
    const v2f axx = {Ax[i], Ax[i]};
    const v2f ayy = {Ay[i], Ay[i]};
    const v2f azz = {Az[i], Az[i]};
#pragma unroll
    for (int j = 0; j < 6; ++j) {
      const v2f dx = axx - Bx[j];
      const v2f dy = ayy - By[j];
      const v2f dz = azz - Bz[j];
      const v2f d2 = dx * dx + dy * dy + dz * dz;
      acc[j & 3] = fminf(acc[j & 3], fminf(d2.x, d2.y));   // v_min3
    }
  }
  float mind2 = fminf(fminf(acc[0], acc[1]), fminf(acc[2], acc[3]));
#pragma unroll
  for (int off = 32; off > 0; off >>= 1)
    mind2 = fminf(mind2, __shfl_down(mind2, off, 64));
  if (lane == 0) minbuf[cellIdx] = sqrtf(fmaxf(mind2, 0.0f));
}

// ---------------------------------------------------------------------------
// Kernel C: masked mean per batch (4 blocks). Reads only mask-true cells, so
// poisoned minbuf entries for masked cells are never touched.
__global__ __launch_bounds__(256) void finalize_kernel(
    const float* __restrict__ min_d, const unsigned char* __restrict__ cm,
    const int* __restrict__ ctrl, float* __restrict__ out) {
  const int b = blockIdx.x;
  const int t = threadIdx.x;
  const int stride4 = ctrl[1];
  const unsigned int* cm32 = (const unsigned int*)cm;

  float sum = 0.0f, cnt = 0.0f;
  for (int i = t; i < R_ * R_; i += 256) {
    const int gi = b * R_ * R_ + i;
    const bool m = stride4 ? (cm32[gi] != 0u) : (cm[gi] != 0);
    if (m) { sum += min_d[gi]; cnt += 1.0f; }
  }
#pragma unroll
  for (int off = 32; off > 0; off >>= 1) {
    sum += __shfl_down(sum, off, 64);
    cnt += __shfl_down(cnt, off, 64);
  }
  __shared__ float ws_[4], wc_[4];
  if ((t & 63) == 0) { ws_[t >> 6] = sum; wc_[t >> 6] = cnt; }
  __syncthreads();
  if (t == 0) {
    out[b] = (ws_[0] + ws_[1] + ws_[2] + ws_[3]) /
             (wc_[0] + wc_[1] + wc_[2] + wc_[3]);
  }
}

// ---------------------------------------------------------------------------
extern "C" void kernel_launch(void* const* d_in, const int* in_sizes, int n_in,
                              void* d_out, int out_size, void* d_ws, size_t ws_size,
                              hipStream_t stream) {
  const float* v1s = (const float*)d_in[0];
  const float* v2s = (const float*)d_in[1];
  const unsigned char* cmaps = (const unsigned char*)d_in[2];
  const int* rid_to_vid = (const int*)d_in[3];
  float* out = (float*)d_out;

  float* minbuf = (float*)d_ws;
  int* ctrl = (int*)((char*)d_ws + 40960);
  float* gbuf = (float*)((char*)d_ws + (64 << 10));

  const int N = in_sizes[0] / (B_ * 3);

  gather_kernel<<<(NROWS * VR_ + 255) / 256, 256, 0, stream>>>(
      v1s, v2s, rid_to_vid, cmaps, gbuf, ctrl, N);
  cell_kernel<<<NBLK_CELL, 256, 0, stream>>>(gbuf, cmaps, minbuf, ctrl);
  finalize_kernel<<<B_, 256, 0, stream>>>(minbuf, cmaps, ctrl, out);
}

// Round 5
// 23.263 us; speedup vs baseline: 4.3998x; 1.0944x over previous
//
#include <hip/hip_runtime.h>

#define B_ 4
#define R_ 48
#define VR_ 96
#define NBLK_CELL (B_ * R_ * 12)     // 2304 blocks: (b, r, quad), 4 waves = 4 s-cells

typedef float v2f __attribute__((ext_vector_type(2)));

// ---------------------------------------------------------------------------
// Detect cmaps element width from its first 256 bytes (wave-parallel, lane t
// of wave 0). int32 layout: bytes at i%4!=0 all zero; f32 layout: contains
// 0x80/0x3F exponent bytes; bool layout: random 0/1 bytes, some nonzero,
// none > 1. Deterministic for fixed inputs; every block computes the same.
__device__ __forceinline__ int detect_stride4(const unsigned char* cm, int t) {
  const unsigned int d = ((const unsigned int*)cm)[t];
  const unsigned int b1 = (d >> 8) & 0xff, b2 = (d >> 16) & 0xff, b3 = d >> 24;
  const unsigned long long nzm = __ballot((b1 | b2 | b3) != 0);
  const unsigned long long bigm = __ballot((b1 > 1) || (b2 > 1) || (b3 > 1));
  return (bigm != 0ull || nzm == 0ull) ? 1 : 0;
}

// ---------------------------------------------------------------------------
// Kernel 1: fused gather + min-distance. One wave per (b,r,s) cell, 4 cells
// per block sharing the g1 row. Block cooperatively gathers 96+384 points
// into SoA LDS, then each wave computes its 96x96 pair min via 12x12 register
// tiles (packed f32). Masked cells contribute nothing; all-masked blocks exit
// before gathering. Plain stores, no cross-block communication.
__global__ __launch_bounds__(256) void fused_cell_kernel(
    const float* __restrict__ v1s, const float* __restrict__ v2s,
    const int* __restrict__ rid_to_vid, const unsigned char* __restrict__ cm,
    float* __restrict__ minbuf, int N) {
  const int bid = blockIdx.x;              // b*(48*12) + r*12 + quad
  const int b = bid / (R_ * 12);
  const int rem = bid % (R_ * 12);
  const int r = rem / 12;
  const int quad = rem % 12;
  const int t = threadIdx.x;
  const int w = t >> 6, lane = t & 63;
  const int s = quad * 4 + w;
  const int cellIdx = (b * R_ + r) * R_ + s;

  __shared__ int stride4_s;
  if (t < 64) {
    const int s4 = detect_stride4(cm, t);
    if (t == 0) stride4_s = s4;
  }
  __syncthreads();
  const int stride4 = stride4_s;

  const bool active = stride4 ? (((const unsigned int*)cm)[cellIdx] != 0u)
                              : (cm[cellIdx] != 0);

  // block-wide any-active (shared-mem flags; ~6% of blocks all-masked)
  __shared__ int flags[4];
  if (lane == 0) flags[w] = active ? 1 : 0;
  __syncthreads();
  if ((flags[0] | flags[1] | flags[2] | flags[3]) == 0) return;  // uniform

  // cooperative gather into SoA LDS: s1 = g1 row r; s2[k] = g2 row quad*4+k
  __shared__ float s1[3 * VR_];
  __shared__ float s2[4][3 * VR_];
  if (t < VR_) {
    const int idx = rid_to_vid[r * VR_ + t];
    const float* src = v1s + ((size_t)b * N + idx) * 3;
    s1[t] = src[0]; s1[VR_ + t] = src[1]; s1[2 * VR_ + t] = src[2];
  }
  for (int p = t; p < 4 * VR_; p += 256) {
    const int srow = p / VR_, v = p % VR_;
    const int idx = rid_to_vid[(quad * 4 + srow) * VR_ + v];
    const float* src = v2s + ((size_t)b * N + idx) * 3;
    s2[srow][v] = src[0]; s2[srow][VR_ + v] = src[1]; s2[srow][2 * VR_ + v] = src[2];
  }
  __syncthreads();
  if (!active) return;                      // wave-uniform, after all barriers

  const float* r2 = s2[w];
  const int hi = lane >> 3, lo = lane & 7;  // 8x8 lane grid, 12x12 pair tile

  float Ax[12], Ay[12], Az[12];
  v2f Bx[6], By[6], Bz[6];
#pragma unroll
  for (int k = 0; k < 3; ++k) {
    *(float4*)&Ax[4 * k] = *(const float4*)(s1            + hi * 12 + 4 * k);
    *(float4*)&Ay[4 * k] = *(const float4*)(s1 +     VR_  + hi * 12 + 4 * k);
    *(float4*)&Az[4 * k] = *(const float4*)(s1 + 2 * VR_  + hi * 12 + 4 * k);
    *(float4*)&Bx[2 * k] = *(const float4*)(r2            + lo * 12 + 4 * k);
    *(float4*)&By[2 * k] = *(const float4*)(r2 +     VR_  + lo * 12 + 4 * k);
    *(float4*)&Bz[2 * k] = *(const float4*)(r2 + 2 * VR_  + lo * 12 + 4 * k);
  }

  float acc[4] = {3.4e38f, 3.4e38f, 3.4e38f, 3.4e38f};
#pragma unroll
  for (int i = 0; i < 12; ++i) {
    const v2f axx = {Ax[i], Ax[i]};
    const v2f ayy = {Ay[i], Ay[i]};
    const v2f azz = {Az[i], Az[i]};
#pragma unroll
    for (int j = 0; j < 6; ++j) {
      const v2f dx = axx - Bx[j];
      const v2f dy = ayy - By[j];
      const v2f dz = azz - Bz[j];
      const v2f d2 = dx * dx + dy * dy + dz * dz;
      acc[j & 3] = fminf(acc[j & 3], fminf(d2.x, d2.y));   // v_min3
    }
  }
  float mind2 = fminf(fminf(acc[0], acc[1]), fminf(acc[2], acc[3]));
#pragma unroll
  for (int off = 32; off > 0; off >>= 1)
    mind2 = fminf(mind2, __shfl_down(mind2, off, 64));
  if (lane == 0) minbuf[cellIdx] = sqrtf(fmaxf(mind2, 0.0f));
}

// ---------------------------------------------------------------------------
// Kernel 2: masked mean per batch (4 blocks). Self-detects cmaps layout.
// Reads only mask-true cells, so poisoned minbuf entries are never touched.
__global__ __launch_bounds__(256) void finalize_kernel(
    const float* __restrict__ min_d, const unsigned char* __restrict__ cm,
    float* __restrict__ out) {
  const int b = blockIdx.x;
  const int t = threadIdx.x;

  __shared__ int stride4_s;
  if (t < 64) {
    const int s4 = detect_stride4(cm, t);
    if (t == 0) stride4_s = s4;
  }
  __syncthreads();
  const int stride4 = stride4_s;
  const unsigned int* cm32 = (const unsigned int*)cm;

  float sum = 0.0f, cnt = 0.0f;
  for (int i = t; i < R_ * R_; i += 256) {
    const int gi = b * R_ * R_ + i;
    const bool m = stride4 ? (cm32[gi] != 0u) : (cm[gi] != 0);
    if (m) { sum += min_d[gi]; cnt += 1.0f; }
  }
#pragma unroll
  for (int off = 32; off > 0; off >>= 1) {
    sum += __shfl_down(sum, off, 64);
    cnt += __shfl_down(cnt, off, 64);
  }
  __shared__ float ws_[4], wc_[4];
  if ((t & 63) == 0) { ws_[t >> 6] = sum; wc_[t >> 6] = cnt; }
  __syncthreads();
  if (t == 0) {
    out[b] = (ws_[0] + ws_[1] + ws_[2] + ws_[3]) /
             (wc_[0] + wc_[1] + wc_[2] + wc_[3]);
  }
}

// ---------------------------------------------------------------------------
extern "C" void kernel_launch(void* const* d_in, const int* in_sizes, int n_in,
                              void* d_out, int out_size, void* d_ws, size_t ws_size,
                              hipStream_t stream) {
  const float* v1s = (const float*)d_in[0];
  const float* v2s = (const float*)d_in[1];
  const unsigned char* cmaps = (const unsigned char*)d_in[2];
  const int* rid_to_vid = (const int*)d_in[3];
  float* out = (float*)d_out;
  float* minbuf = (float*)d_ws;            // 9216 floats = 36 KB

  const int N = in_sizes[0] / (B_ * 3);

  fused_cell_kernel<<<NBLK_CELL, 256, 0, stream>>>(
      v1s, v2s, rid_to_vid, cmaps, minbuf, N);
  finalize_kernel<<<B_, 256, 0, stream>>>(minbuf, cmaps, out);
}